// Round 16
// baseline (143.467 us; speedup 1.0000x reference)
//
#include <hip/hip_runtime.h>

// OurButterflyLayer: N=4096, LOGN=12, IN=1024, OUT=4096, BATCH=8192
//
// out[s,j] = scale[j] * z_s[src[j]],  z_s = 10-stage butterfly (stages 0..9)
// on the 1024-float input row s; stages 10,11 + out-row gather fold into
// per-output (scale, src) pairs (elements >=1024 stay zero through stages
// 0..9 since all strides < 1024).
//
// Round-16: R14's persistent-block chunk pipeline with the spill fixed.
// R14 regressed ONLY because __launch_bounds__(512,2) capped VGPR at 128
// while the pipeline's live set is ~130 -> ~240 MB scratch traffic (counters:
// FETCH 104 MB, WRITE 304 MB). __launch_bounds__(512,1) keeps the same
// occupancy (1 block/CU, LDS-bound) but allows up to 256 VGPR -> no spill.
// Flow per wave (4 samples as 2 chunks):
//   bf(c0) -> zwrite0 -> issue c1 input loads -> emit0 (stores || loads)
//   -> bf(c1) (LDS-only; c0 store queue drains underneath) -> emit1.
// All 20 coeff rows in 80 KB swizzled LDS, staged ONCE per CU (grid 256).
// Butterfly/exchange/slot/epilogue bodies = R13 verified code.

typedef float f4 __attribute__((ext_vector_type(4)));
typedef float f2 __attribute__((ext_vector_type(2)));
typedef int   i4 __attribute__((ext_vector_type(4)));

__device__ __forceinline__ int swz(int e) {
    // XOR float-index bits [6:5] into [3:2]: keeps float4 alignment; makes
    // 64B-stride LDS coeff accesses bank-conflict-free.
    return e ^ (((e >> 5) & 3) << 2);
}

template<int CTRL>
__device__ __forceinline__ float dppx(float x) {
    int xi = __builtin_bit_cast(int, x);
    int r  = __builtin_amdgcn_update_dpp(xi, xi, CTRL, 0xF, 0xF, true);
    return __builtin_bit_cast(float, r);
}
// ctrl: quad_perm(1,0,3,2)=0xB1 (lane^1), quad_perm(2,3,0,1)=0x4E (lane^2),
// row_ror:8=0x128 (lane^8 within 16-lane row). Verified R4/R6/R7/R10/R13.

__global__ void __launch_bounds__(256) bfly_prep(
    const float* __restrict__ lp, const int* __restrict__ orow,
    float* __restrict__ scale, int* __restrict__ src2)
{
    int j = blockIdx.x * 256 + threadIdx.x;
    if (j >= 4096) return;
    int r = orow[j];
    int c = r & 1023;
    int u = r & 2047;
    const float* A10 = lp + 20 * 4096;
    const float* B10 = lp + 21 * 4096;
    const float* A11 = lp + 22 * 4096;
    const float* B11 = lp + 23 * 4096;
    float f11 = (r & 2048) ? B11[u] : A11[u];
    float f10 = (r & 1024) ? B10[c] : A10[c];
    scale[j] = f11 * f10;
    // f2-slot index with pair-preserving bank spread:
    // pz(c) = c ^ (((c>>4)&7)<<1)   (matches z-write slot algebra below)
    src2[j] = c ^ (((c >> 4) & 7) << 1);
}

__device__ __forceinline__ void load_chunk(
    const float* __restrict__ inp, int s0, int lane, float (&x)[2][16])
{
    #pragma unroll
    for (int m = 0; m < 2; ++m) {
        const f4* p = reinterpret_cast<const f4*>(inp + (size_t)(s0 + m) * 1024 + lane * 16);
        #pragma unroll
        for (int c = 0; c < 4; ++c) {
            f4 v = p[c];
            x[m][4*c+0] = v.x; x[m][4*c+1] = v.y; x[m][4*c+2] = v.z; x[m][4*c+3] = v.w;
        }
    }
}

__device__ __forceinline__ void butterfly(
    const float* __restrict__ cf, int lane, float (&x)[2][16])
{
    // ---- stages 0,1 (s=1,2): pairs within each f4 quarter ----
    #pragma unroll
    for (int i = 0; i < 2; ++i) {
        const float* arow = &cf[(size_t)(2*i)     * 1024];
        const float* brow = &cf[(size_t)(2*i + 1) * 1024];
        #pragma unroll
        for (int c = 0; c < 4; ++c) {
            f4 va = *reinterpret_cast<const f4*>(&arow[swz(lane * 16 + 4 * c)]);
            f4 vb = *reinterpret_cast<const f4*>(&brow[swz(lane * 16 + 4 * c)]);
            #pragma unroll
            for (int m = 0; m < 2; ++m) {
                float* xm = x[m];
                if (i == 0) {          // pairs (0,1),(2,3)
                    float lo0 = xm[4*c+0], hi0 = xm[4*c+1];
                    xm[4*c+0] = va[0] * lo0 + vb[1] * hi0;
                    xm[4*c+1] = va[1] * hi0 + vb[0] * lo0;
                    float lo1 = xm[4*c+2], hi1 = xm[4*c+3];
                    xm[4*c+2] = va[2] * lo1 + vb[3] * hi1;
                    xm[4*c+3] = va[3] * hi1 + vb[2] * lo1;
                } else {               // pairs (0,2),(1,3)
                    float lo0 = xm[4*c+0], hi0 = xm[4*c+2];
                    xm[4*c+0] = va[0] * lo0 + vb[2] * hi0;
                    xm[4*c+2] = va[2] * hi0 + vb[0] * lo0;
                    float lo1 = xm[4*c+1], hi1 = xm[4*c+3];
                    xm[4*c+1] = va[1] * lo1 + vb[3] * hi1;
                    xm[4*c+3] = va[3] * hi1 + vb[1] * lo1;
                }
            }
        }
    }

    // ---- stages 2,3 (s=4,8): pairs across quarters ----
    #pragma unroll
    for (int i = 2; i < 4; ++i) {
        const float* arow = &cf[(size_t)(2*i)     * 1024];
        const float* brow = &cf[(size_t)(2*i + 1) * 1024];
        #pragma unroll
        for (int g = 0; g < 2; ++g) {
            const int q0 = (i == 2) ? 2 * g : g;       // s=4: (0,1),(2,3)
            const int q1 = (i == 2) ? q0 + 1 : q0 + 2; // s=8: (0,2),(1,3)
            f4 va0 = *reinterpret_cast<const f4*>(&arow[swz(lane * 16 + 4 * q0)]);
            f4 va1 = *reinterpret_cast<const f4*>(&arow[swz(lane * 16 + 4 * q1)]);
            f4 vb0 = *reinterpret_cast<const f4*>(&brow[swz(lane * 16 + 4 * q0)]);
            f4 vb1 = *reinterpret_cast<const f4*>(&brow[swz(lane * 16 + 4 * q1)]);
            #pragma unroll
            for (int m = 0; m < 2; ++m) {
                float* xm = x[m];
                #pragma unroll
                for (int e = 0; e < 4; ++e) {
                    float lo = xm[4*q0+e], hi = xm[4*q1+e];
                    xm[4*q0+e] = va0[e] * lo + vb1[e] * hi;
                    xm[4*q1+e] = va1[e] * hi + vb0[e] * lo;
                }
            }
        }
    }

    // ---- stage 4 (d=1): DPP quad_perm exchange; coeff rows 8,9 ----
    {
        const float* arow = &cf[(size_t)8 * 1024];
        const float* brow = &cf[(size_t)9 * 1024];
        #pragma unroll
        for (int c = 0; c < 4; ++c) {
            f4 va = *reinterpret_cast<const f4*>(&arow[swz(lane * 16 + 4 * c)]);
            f4 vb = *reinterpret_cast<const f4*>(&brow[swz((lane ^ 1) * 16 + 4 * c)]);
            #pragma unroll
            for (int m = 0; m < 2; ++m) {
                #pragma unroll
                for (int e = 0; e < 4; ++e) {
                    float v = x[m][4*c+e];
                    x[m][4*c+e] = va[e] * v + vb[e] * dppx<0xB1>(v);
                }
            }
        }
    }

    // ---- stages 5..9 (d=2,4,8,16,32): coeff rows 10..19 ----
    #pragma unroll
    for (int i = 5; i < 10; ++i) {
        const int d = 1 << (i - 4);
        const float* arow = &cf[(size_t)(2*i)     * 1024];
        const float* brow = &cf[(size_t)(2*i + 1) * 1024];
        #pragma unroll
        for (int c = 0; c < 4; ++c) {
            f4 va = *reinterpret_cast<const f4*>(&arow[swz(lane * 16 + 4 * c)]);
            f4 vb = *reinterpret_cast<const f4*>(&brow[swz((lane ^ d) * 16 + 4 * c)]);
            #pragma unroll
            for (int m = 0; m < 2; ++m) {
                #pragma unroll
                for (int e = 0; e < 4; ++e) {
                    float v = x[m][4*c+e];
                    float xp = (d == 2) ? dppx<0x4E>(v)
                             : (d == 8) ? dppx<0x128>(v)
                             :            __shfl_xor(v, d, 64);   // d = 4,16,32
                    x[m][4*c+e] = va[e] * v + vb[e] * xp;
                }
            }
        }
    }
}

__device__ __forceinline__ void zwrite(
    float* __restrict__ zz, int lane, const float (&x)[2][16])
{
    // f2-slot pi = pz(c) = c ^ (((c>>4)&7)<<1) for element c = lane*16+k
    const int km0 = (lane & 7) << 1;
    #pragma unroll
    for (int k = 0; k < 16; k += 2) {
        int pi = lane * 16 + (k ^ km0);
        f4 v = { x[0][k], x[1][k], x[0][k+1], x[1][k+1] };
        *reinterpret_cast<f4*>(&zz[2 * pi]) = v;
    }
}

__device__ __forceinline__ void emit(
    const float* __restrict__ zz, const int* __restrict__ src2,
    const float* __restrict__ scale, float* __restrict__ out,
    int s0, int lane)
{
    const i4* srv = reinterpret_cast<const i4*>(src2);
    const f4* scv = reinterpret_cast<const f4*>(scale);
    f4* o0 = reinterpret_cast<f4*>(out + (size_t)s0 * 4096);
    f4* o1 = reinterpret_cast<f4*>(out + (size_t)(s0 + 1) * 4096);

    i4 si = srv[lane];
    f4 sc = scv[lane];
    #pragma unroll
    for (int it = 0; it < 16; ++it) {
        i4 si_c = si;
        f4 sc_c = sc;
        if (it + 1 < 16) {                      // prefetch next iteration
            si = srv[(it + 1) * 64 + lane];
            sc = scv[(it + 1) * 64 + lane];
        }
        int j4 = it * 64 + lane;
        f2 vx = *reinterpret_cast<const f2*>(&zz[2 * si_c.x]);
        f2 vy = *reinterpret_cast<const f2*>(&zz[2 * si_c.y]);
        f2 vz = *reinterpret_cast<const f2*>(&zz[2 * si_c.z]);
        f2 vw = *reinterpret_cast<const f2*>(&zz[2 * si_c.w]);
        f4 r0 = { sc_c.x * vx.x, sc_c.y * vy.x, sc_c.z * vz.x, sc_c.w * vw.x };
        f4 r1 = { sc_c.x * vx.y, sc_c.y * vy.y, sc_c.z * vz.y, sc_c.w * vw.y };
        o0[j4] = r0;
        o1[j4] = r1;
    }
}

__global__ void __launch_bounds__(512, 1) bfly_main(
    const float* __restrict__ inp, const float* __restrict__ lp,
    const float* __restrict__ scale, const int* __restrict__ src2,
    float* __restrict__ out)
{
    // [0, 20480): 20 coeff rows (stages 0..9 a,b), swizzled. persistent.
    // [20480, 36864): 8 waves x 1024 paired-f2 z slots (8 KB each).
    __shared__ __align__(16) float cf[20 * 1024 + 8 * 2048];
    const int t = threadIdx.x;
    const int wave = t >> 6, lane = t & 63;

    // cooperative coeff staging: rows 0..19 of lp (first 1024 floats each);
    // 512 threads stage two rows per step.
    #pragma unroll
    for (int step = 0; step < 10; ++step) {
        const int q = 2 * step + (t >> 8);
        const int e = (t & 255) * 4;
        const f4 v = *reinterpret_cast<const f4*>(lp + (size_t)q * 4096 + e);
        *reinterpret_cast<f4*>(&cf[q * 1024 + swz(e)]) = v;
    }

    const int sBase = blockIdx.x * 32 + wave * 4;   // 4 samples per wave
    float* zz = &cf[20 * 1024 + (size_t)wave * 2048];

    float x[2][16];
    load_chunk(inp, sBase, lane, x);                // chunk 0 input

    __syncthreads();   // cf ready — the only barrier in the kernel

    butterfly(cf, lane, x);
    zwrite(zz, lane, x);

    float y[2][16];
    load_chunk(inp, sBase + 2, lane, y);            // chunk 1 loads in flight

    emit(zz, src2, scale, out, sBase, lane);        // chunk 0 stores || loads

    butterfly(cf, lane, y);                         // || chunk 0 store drain
    zwrite(zz, lane, y);                            // after emit0 reads (in-order DS)
    emit(zz, src2, scale, out, sBase + 2, lane);
}

extern "C" void kernel_launch(void* const* d_in, const int* in_sizes, int n_in,
                              void* d_out, int out_size, void* d_ws, size_t ws_size,
                              hipStream_t stream) {
    const float* inp  = (const float*)d_in[0];   // (8192, 1024) f32
    const float* lp   = (const float*)d_in[1];   // (24, 4096)  f32
    const int*   orow = (const int*)d_in[2];     // (4096,)     i32
    float* out = (float*)d_out;                  // (8192, 4096) f32

    float* scale = (float*)d_ws;                       // 4096 f32
    int*   src2  = (int*)((char*)d_ws + 4096 * 4);     // 4096 i32 (f2-slot idx)

    bfly_prep<<<16, 256, 0, stream>>>(lp, orow, scale, src2);
    bfly_main<<<256, 512, 0, stream>>>(inp, lp, scale, src2, out);
}

// Round 17
// 142.845 us; speedup vs baseline: 1.0044x; 1.0044x over previous
//
#include <hip/hip_runtime.h>

// OurButterflyLayer: N=4096, LOGN=12, IN=1024, OUT=4096, BATCH=8192
//
// out[s,j] = scale[j] * z_s[src[j]],  z_s = 10-stage butterfly (stages 0..9)
// on the 1024-float input row s; stages 10,11 + out-row gather fold into
// per-output (scale, src) pairs (elements >=1024 stay zero through stages
// 0..9 since all strides < 1024).
//
// Round-17: chunk pipeline with REGISTER REUSE (no second array).
// R14/R16 spilled because chunk-1 lived in y[2][16] while emit(chunk0) ran
// (VGPR cap for 512-thr blocks is 128). Fix: after zwrite(c0), x is dead
// (c0's data lives in LDS) -> load c1 into the SAME x array. Live set ==
// R13's (proven no-spill at 128 VGPR). Flow per wave (4 samples):
//   load x(c0) -> stage -> barrier -> bf(x) -> zwrite -> load x(c1)
//   -> emit(c0) (stores || c1 loads) -> bf(x) -> zwrite -> emit(c1).
// Grid 256 x 512 thr = 1 persistent block/CU: coeffs staged ONCE per CU.
// All bodies = R13 verified code. Plain loads/stores.

typedef float f4 __attribute__((ext_vector_type(4)));
typedef float f2 __attribute__((ext_vector_type(2)));
typedef int   i4 __attribute__((ext_vector_type(4)));

__device__ __forceinline__ int swz(int e) {
    // XOR float-index bits [6:5] into [3:2]: keeps float4 alignment; makes
    // 64B-stride LDS coeff accesses bank-conflict-free.
    return e ^ (((e >> 5) & 3) << 2);
}

template<int CTRL>
__device__ __forceinline__ float dppx(float x) {
    int xi = __builtin_bit_cast(int, x);
    int r  = __builtin_amdgcn_update_dpp(xi, xi, CTRL, 0xF, 0xF, true);
    return __builtin_bit_cast(float, r);
}
// ctrl: quad_perm(1,0,3,2)=0xB1 (lane^1), quad_perm(2,3,0,1)=0x4E (lane^2),
// row_ror:8=0x128 (lane^8 within 16-lane row). Verified R4/R6/R7/R10/R13.

__global__ void __launch_bounds__(256) bfly_prep(
    const float* __restrict__ lp, const int* __restrict__ orow,
    float* __restrict__ scale, int* __restrict__ src2)
{
    int j = blockIdx.x * 256 + threadIdx.x;
    if (j >= 4096) return;
    int r = orow[j];
    int c = r & 1023;
    int u = r & 2047;
    const float* A10 = lp + 20 * 4096;
    const float* B10 = lp + 21 * 4096;
    const float* A11 = lp + 22 * 4096;
    const float* B11 = lp + 23 * 4096;
    float f11 = (r & 2048) ? B11[u] : A11[u];
    float f10 = (r & 1024) ? B10[c] : A10[c];
    scale[j] = f11 * f10;
    // f2-slot index with pair-preserving bank spread:
    // pz(c) = c ^ (((c>>4)&7)<<1)   (matches z-write slot algebra below)
    src2[j] = c ^ (((c >> 4) & 7) << 1);
}

__device__ __forceinline__ void load_chunk(
    const float* __restrict__ inp, int s0, int lane, float (&x)[2][16])
{
    #pragma unroll
    for (int m = 0; m < 2; ++m) {
        const f4* p = reinterpret_cast<const f4*>(inp + (size_t)(s0 + m) * 1024 + lane * 16);
        #pragma unroll
        for (int c = 0; c < 4; ++c) {
            f4 v = p[c];
            x[m][4*c+0] = v.x; x[m][4*c+1] = v.y; x[m][4*c+2] = v.z; x[m][4*c+3] = v.w;
        }
    }
}

__device__ __forceinline__ void butterfly(
    const float* __restrict__ cf, int lane, float (&x)[2][16])
{
    // ---- stages 0,1 (s=1,2): pairs within each f4 quarter ----
    #pragma unroll
    for (int i = 0; i < 2; ++i) {
        const float* arow = &cf[(size_t)(2*i)     * 1024];
        const float* brow = &cf[(size_t)(2*i + 1) * 1024];
        #pragma unroll
        for (int c = 0; c < 4; ++c) {
            f4 va = *reinterpret_cast<const f4*>(&arow[swz(lane * 16 + 4 * c)]);
            f4 vb = *reinterpret_cast<const f4*>(&brow[swz(lane * 16 + 4 * c)]);
            #pragma unroll
            for (int m = 0; m < 2; ++m) {
                float* xm = x[m];
                if (i == 0) {          // pairs (0,1),(2,3)
                    float lo0 = xm[4*c+0], hi0 = xm[4*c+1];
                    xm[4*c+0] = va[0] * lo0 + vb[1] * hi0;
                    xm[4*c+1] = va[1] * hi0 + vb[0] * lo0;
                    float lo1 = xm[4*c+2], hi1 = xm[4*c+3];
                    xm[4*c+2] = va[2] * lo1 + vb[3] * hi1;
                    xm[4*c+3] = va[3] * hi1 + vb[2] * lo1;
                } else {               // pairs (0,2),(1,3)
                    float lo0 = xm[4*c+0], hi0 = xm[4*c+2];
                    xm[4*c+0] = va[0] * lo0 + vb[2] * hi0;
                    xm[4*c+2] = va[2] * hi0 + vb[0] * lo0;
                    float lo1 = xm[4*c+1], hi1 = xm[4*c+3];
                    xm[4*c+1] = va[1] * lo1 + vb[3] * hi1;
                    xm[4*c+3] = va[3] * hi1 + vb[1] * lo1;
                }
            }
        }
    }

    // ---- stages 2,3 (s=4,8): pairs across quarters ----
    #pragma unroll
    for (int i = 2; i < 4; ++i) {
        const float* arow = &cf[(size_t)(2*i)     * 1024];
        const float* brow = &cf[(size_t)(2*i + 1) * 1024];
        #pragma unroll
        for (int g = 0; g < 2; ++g) {
            const int q0 = (i == 2) ? 2 * g : g;       // s=4: (0,1),(2,3)
            const int q1 = (i == 2) ? q0 + 1 : q0 + 2; // s=8: (0,2),(1,3)
            f4 va0 = *reinterpret_cast<const f4*>(&arow[swz(lane * 16 + 4 * q0)]);
            f4 va1 = *reinterpret_cast<const f4*>(&arow[swz(lane * 16 + 4 * q1)]);
            f4 vb0 = *reinterpret_cast<const f4*>(&brow[swz(lane * 16 + 4 * q0)]);
            f4 vb1 = *reinterpret_cast<const f4*>(&brow[swz(lane * 16 + 4 * q1)]);
            #pragma unroll
            for (int m = 0; m < 2; ++m) {
                float* xm = x[m];
                #pragma unroll
                for (int e = 0; e < 4; ++e) {
                    float lo = xm[4*q0+e], hi = xm[4*q1+e];
                    xm[4*q0+e] = va0[e] * lo + vb1[e] * hi;
                    xm[4*q1+e] = va1[e] * hi + vb0[e] * lo;
                }
            }
        }
    }

    // ---- stage 4 (d=1): DPP quad_perm exchange; coeff rows 8,9 ----
    {
        const float* arow = &cf[(size_t)8 * 1024];
        const float* brow = &cf[(size_t)9 * 1024];
        #pragma unroll
        for (int c = 0; c < 4; ++c) {
            f4 va = *reinterpret_cast<const f4*>(&arow[swz(lane * 16 + 4 * c)]);
            f4 vb = *reinterpret_cast<const f4*>(&brow[swz((lane ^ 1) * 16 + 4 * c)]);
            #pragma unroll
            for (int m = 0; m < 2; ++m) {
                #pragma unroll
                for (int e = 0; e < 4; ++e) {
                    float v = x[m][4*c+e];
                    x[m][4*c+e] = va[e] * v + vb[e] * dppx<0xB1>(v);
                }
            }
        }
    }

    // ---- stages 5..9 (d=2,4,8,16,32): coeff rows 10..19 ----
    #pragma unroll
    for (int i = 5; i < 10; ++i) {
        const int d = 1 << (i - 4);
        const float* arow = &cf[(size_t)(2*i)     * 1024];
        const float* brow = &cf[(size_t)(2*i + 1) * 1024];
        #pragma unroll
        for (int c = 0; c < 4; ++c) {
            f4 va = *reinterpret_cast<const f4*>(&arow[swz(lane * 16 + 4 * c)]);
            f4 vb = *reinterpret_cast<const f4*>(&brow[swz((lane ^ d) * 16 + 4 * c)]);
            #pragma unroll
            for (int m = 0; m < 2; ++m) {
                #pragma unroll
                for (int e = 0; e < 4; ++e) {
                    float v = x[m][4*c+e];
                    float xp = (d == 2) ? dppx<0x4E>(v)
                             : (d == 8) ? dppx<0x128>(v)
                             :            __shfl_xor(v, d, 64);   // d = 4,16,32
                    x[m][4*c+e] = va[e] * v + vb[e] * xp;
                }
            }
        }
    }
}

__device__ __forceinline__ void zwrite(
    float* __restrict__ zz, int lane, const float (&x)[2][16])
{
    // f2-slot pi = pz(c) = c ^ (((c>>4)&7)<<1) for element c = lane*16+k
    const int km0 = (lane & 7) << 1;
    #pragma unroll
    for (int k = 0; k < 16; k += 2) {
        int pi = lane * 16 + (k ^ km0);
        f4 v = { x[0][k], x[1][k], x[0][k+1], x[1][k+1] };
        *reinterpret_cast<f4*>(&zz[2 * pi]) = v;
    }
}

__device__ __forceinline__ void emit(
    const float* __restrict__ zz, const int* __restrict__ src2,
    const float* __restrict__ scale, float* __restrict__ out,
    int s0, int lane)
{
    const i4* srv = reinterpret_cast<const i4*>(src2);
    const f4* scv = reinterpret_cast<const f4*>(scale);
    f4* o0 = reinterpret_cast<f4*>(out + (size_t)s0 * 4096);
    f4* o1 = reinterpret_cast<f4*>(out + (size_t)(s0 + 1) * 4096);

    i4 si = srv[lane];
    f4 sc = scv[lane];
    #pragma unroll
    for (int it = 0; it < 16; ++it) {
        i4 si_c = si;
        f4 sc_c = sc;
        if (it + 1 < 16) {                      // prefetch next iteration
            si = srv[(it + 1) * 64 + lane];
            sc = scv[(it + 1) * 64 + lane];
        }
        int j4 = it * 64 + lane;
        f2 vx = *reinterpret_cast<const f2*>(&zz[2 * si_c.x]);
        f2 vy = *reinterpret_cast<const f2*>(&zz[2 * si_c.y]);
        f2 vz = *reinterpret_cast<const f2*>(&zz[2 * si_c.z]);
        f2 vw = *reinterpret_cast<const f2*>(&zz[2 * si_c.w]);
        f4 r0 = { sc_c.x * vx.x, sc_c.y * vy.x, sc_c.z * vz.x, sc_c.w * vw.x };
        f4 r1 = { sc_c.x * vx.y, sc_c.y * vy.y, sc_c.z * vz.y, sc_c.w * vw.y };
        o0[j4] = r0;
        o1[j4] = r1;
    }
}

__global__ void __launch_bounds__(512, 2) bfly_main(
    const float* __restrict__ inp, const float* __restrict__ lp,
    const float* __restrict__ scale, const int* __restrict__ src2,
    float* __restrict__ out)
{
    // [0, 20480): 20 coeff rows (stages 0..9 a,b), swizzled. persistent.
    // [20480, 36864): 8 waves x 1024 paired-f2 z slots (8 KB each).
    __shared__ __align__(16) float cf[20 * 1024 + 8 * 2048];
    const int t = threadIdx.x;
    const int wave = t >> 6, lane = t & 63;

    // cooperative coeff staging: rows 0..19 of lp (first 1024 floats each);
    // 512 threads stage two rows per step. ONCE per CU (grid 256).
    #pragma unroll
    for (int step = 0; step < 10; ++step) {
        const int q = 2 * step + (t >> 8);
        const int e = (t & 255) * 4;
        const f4 v = *reinterpret_cast<const f4*>(lp + (size_t)q * 4096 + e);
        *reinterpret_cast<f4*>(&cf[q * 1024 + swz(e)]) = v;
    }

    const int sBase = blockIdx.x * 32 + wave * 4;   // 4 samples per wave
    float* zz = &cf[20 * 1024 + (size_t)wave * 2048];

    float x[2][16];
    load_chunk(inp, sBase, lane, x);                // chunk 0 input

    __syncthreads();   // cf ready — the only barrier in the kernel

    butterfly(cf, lane, x);
    zwrite(zz, lane, x);                            // c0 now lives in LDS

    load_chunk(inp, sBase + 2, lane, x);            // REUSE x: c1 loads fly

    emit(zz, src2, scale, out, sBase, lane);        // c0 stores || c1 loads

    butterfly(cf, lane, x);                         // || c0 store drain
    zwrite(zz, lane, x);                            // after emit0 reads (in-order DS)
    emit(zz, src2, scale, out, sBase + 2, lane);
}

extern "C" void kernel_launch(void* const* d_in, const int* in_sizes, int n_in,
                              void* d_out, int out_size, void* d_ws, size_t ws_size,
                              hipStream_t stream) {
    const float* inp  = (const float*)d_in[0];   // (8192, 1024) f32
    const float* lp   = (const float*)d_in[1];   // (24, 4096)  f32
    const int*   orow = (const int*)d_in[2];     // (4096,)     i32
    float* out = (float*)d_out;                  // (8192, 4096) f32

    float* scale = (float*)d_ws;                       // 4096 f32
    int*   src2  = (int*)((char*)d_ws + 4096 * 4);     // 4096 i32 (f2-slot idx)

    bfly_prep<<<16, 256, 0, stream>>>(lp, orow, scale, src2);
    bfly_main<<<256, 512, 0, stream>>>(inp, lp, scale, src2, out);
}

// Round 19
// 41.755 us; speedup vs baseline: 3.4359x; 3.4210x over previous
//
#include <hip/hip_runtime.h>

// OurButterflyLayer: N=4096, LOGN=12, IN=1024, OUT=4096, BATCH=8192
//
// out[s,j] = scale[j] * z_s[src[j]],  z_s = 10-stage butterfly (stages 0..9)
// on the 1024-float input row s; stages 10,11 + out-row gather fold into
// per-output (scale, src) pairs (elements >=1024 stay zero through stages
// 0..9 since all strides < 1024).
//
// Round-19: R13 (best, 42.5 us) with d=16,32 exchanges on the VALU pipe via
// the gfx950 BUILTIN __builtin_amdgcn_permlane16/32_swap. R18's inline-asm
// version failed because DPP-class crossbar reads of a just-written VGPR
// need compiler-inserted hazard wait-states; the builtin gets them. With
// both inputs = x the swap returns r.x=[x0,x0,x2,x2], r.y=[x1,x1,x3,x3]
// (16-lane rows), so r.x^r.y^x == x[lane^16] for EVERY lane, direction-proof.
// d=4 stays __shfl_xor (verified); d=1,2,8 stay DPP (verified). Everything
// else is R13 byte-identical: 512 blocks x 512 thr, all 20 coeff rows in
// 80 KB swizzled LDS, 8 KB/wave paired-z scratch, one barrier, plain
// loads/stores, pipelined f2-paired epilogue.

typedef float f4 __attribute__((ext_vector_type(4)));
typedef float f2 __attribute__((ext_vector_type(2)));
typedef int   i4 __attribute__((ext_vector_type(4)));

__device__ __forceinline__ int swz(int e) {
    // XOR float-index bits [6:5] into [3:2]: keeps float4 alignment; makes
    // 64B-stride LDS coeff accesses bank-conflict-free.
    return e ^ (((e >> 5) & 3) << 2);
}

template<int CTRL>
__device__ __forceinline__ float dppx(float x) {
    int xi = __builtin_bit_cast(int, x);
    int r  = __builtin_amdgcn_update_dpp(xi, xi, CTRL, 0xF, 0xF, true);
    return __builtin_bit_cast(float, r);
}
// ctrl: quad_perm(1,0,3,2)=0xB1 (lane^1), quad_perm(2,3,0,1)=0x4E (lane^2),
// row_ror:8=0x128 (lane^8 within 16-lane row). Verified R4/R6/R7/R10/R13.

#if __has_builtin(__builtin_amdgcn_permlane16_swap) && __has_builtin(__builtin_amdgcn_permlane32_swap)
#define HAVE_PERMLANE_SWAP 1
// lane^16 / lane^32 partner via permlane swap builtin: both swapped
// registers come back; XOR-combine with x is exact and direction-proof.
__device__ __forceinline__ float xswap16(float x) {
    unsigned xi = __builtin_bit_cast(unsigned, x);
    auto r = __builtin_amdgcn_permlane16_swap(xi, xi, false, false);
    return __builtin_bit_cast(float, r[0] ^ r[1] ^ xi);
}
__device__ __forceinline__ float xswap32(float x) {
    unsigned xi = __builtin_bit_cast(unsigned, x);
    auto r = __builtin_amdgcn_permlane32_swap(xi, xi, false, false);
    return __builtin_bit_cast(float, r[0] ^ r[1] ^ xi);
}
#else
#define HAVE_PERMLANE_SWAP 0
__device__ __forceinline__ float xswap16(float x) { return __shfl_xor(x, 16, 64); }
__device__ __forceinline__ float xswap32(float x) { return __shfl_xor(x, 32, 64); }
#endif

__global__ void __launch_bounds__(256) bfly_prep(
    const float* __restrict__ lp, const int* __restrict__ orow,
    float* __restrict__ scale, int* __restrict__ src2)
{
    int j = blockIdx.x * 256 + threadIdx.x;
    if (j >= 4096) return;
    int r = orow[j];
    int c = r & 1023;
    int u = r & 2047;
    const float* A10 = lp + 20 * 4096;
    const float* B10 = lp + 21 * 4096;
    const float* A11 = lp + 22 * 4096;
    const float* B11 = lp + 23 * 4096;
    float f11 = (r & 2048) ? B11[u] : A11[u];
    float f10 = (r & 1024) ? B10[c] : A10[c];
    scale[j] = f11 * f10;
    // f2-slot index with pair-preserving bank spread:
    // pz(c) = c ^ (((c>>4)&7)<<1)   (matches z-write slot algebra below)
    src2[j] = c ^ (((c >> 4) & 7) << 1);
}

__global__ void __launch_bounds__(512, 2) bfly_main(
    const float* __restrict__ inp, const float* __restrict__ lp,
    const float* __restrict__ scale, const int* __restrict__ src2,
    float* __restrict__ out)
{
    // [0, 20480): 20 coeff rows (stages 0..9 a,b), swizzled. persistent.
    // [20480, 36864): 8 waves x 1024 paired-f2 z slots (8 KB each).
    __shared__ __align__(16) float cf[20 * 1024 + 8 * 2048];
    const int t = threadIdx.x;
    const int wave = t >> 6, lane = t & 63;

    // cooperative coeff staging: rows 0..19 of lp (first 1024 floats each);
    // 512 threads stage two rows per step.
    #pragma unroll
    for (int step = 0; step < 10; ++step) {
        const int q = 2 * step + (t >> 8);
        const int e = (t & 255) * 4;
        const f4 v = *reinterpret_cast<const f4*>(lp + (size_t)q * 4096 + e);
        *reinterpret_cast<f4*>(&cf[q * 1024 + swz(e)]) = v;
    }

    const int sBase = blockIdx.x * 16 + wave * 2;   // 2 samples per wave
    float x[2][16];
    #pragma unroll
    for (int m = 0; m < 2; ++m) {
        const f4* p = reinterpret_cast<const f4*>(inp + (size_t)(sBase + m) * 1024 + lane * 16);
        #pragma unroll
        for (int c = 0; c < 4; ++c) {
            f4 v = p[c];
            x[m][4*c+0] = v.x; x[m][4*c+1] = v.y; x[m][4*c+2] = v.z; x[m][4*c+3] = v.w;
        }
    }

    __syncthreads();   // cf ready — the only barrier in the kernel

    // ---- stages 0,1 (s=1,2): pairs within each f4 quarter; coeff from LDS ----
    #pragma unroll
    for (int i = 0; i < 2; ++i) {
        const float* arow = &cf[(size_t)(2*i)     * 1024];
        const float* brow = &cf[(size_t)(2*i + 1) * 1024];
        #pragma unroll
        for (int c = 0; c < 4; ++c) {
            f4 va = *reinterpret_cast<const f4*>(&arow[swz(lane * 16 + 4 * c)]);
            f4 vb = *reinterpret_cast<const f4*>(&brow[swz(lane * 16 + 4 * c)]);
            #pragma unroll
            for (int m = 0; m < 2; ++m) {
                float* xm = x[m];
                if (i == 0) {          // pairs (0,1),(2,3)
                    float lo0 = xm[4*c+0], hi0 = xm[4*c+1];
                    xm[4*c+0] = va[0] * lo0 + vb[1] * hi0;
                    xm[4*c+1] = va[1] * hi0 + vb[0] * lo0;
                    float lo1 = xm[4*c+2], hi1 = xm[4*c+3];
                    xm[4*c+2] = va[2] * lo1 + vb[3] * hi1;
                    xm[4*c+3] = va[3] * hi1 + vb[2] * lo1;
                } else {               // pairs (0,2),(1,3)
                    float lo0 = xm[4*c+0], hi0 = xm[4*c+2];
                    xm[4*c+0] = va[0] * lo0 + vb[2] * hi0;
                    xm[4*c+2] = va[2] * hi0 + vb[0] * lo0;
                    float lo1 = xm[4*c+1], hi1 = xm[4*c+3];
                    xm[4*c+1] = va[1] * lo1 + vb[3] * hi1;
                    xm[4*c+3] = va[3] * hi1 + vb[1] * lo1;
                }
            }
        }
    }

    // ---- stages 2,3 (s=4,8): pairs across quarters; coeff from LDS ----
    #pragma unroll
    for (int i = 2; i < 4; ++i) {
        const float* arow = &cf[(size_t)(2*i)     * 1024];
        const float* brow = &cf[(size_t)(2*i + 1) * 1024];
        #pragma unroll
        for (int g = 0; g < 2; ++g) {
            const int q0 = (i == 2) ? 2 * g : g;       // s=4: (0,1),(2,3)
            const int q1 = (i == 2) ? q0 + 1 : q0 + 2; // s=8: (0,2),(1,3)
            f4 va0 = *reinterpret_cast<const f4*>(&arow[swz(lane * 16 + 4 * q0)]);
            f4 va1 = *reinterpret_cast<const f4*>(&arow[swz(lane * 16 + 4 * q1)]);
            f4 vb0 = *reinterpret_cast<const f4*>(&brow[swz(lane * 16 + 4 * q0)]);
            f4 vb1 = *reinterpret_cast<const f4*>(&brow[swz(lane * 16 + 4 * q1)]);
            #pragma unroll
            for (int m = 0; m < 2; ++m) {
                float* xm = x[m];
                #pragma unroll
                for (int e = 0; e < 4; ++e) {
                    float lo = xm[4*q0+e], hi = xm[4*q1+e];
                    xm[4*q0+e] = va0[e] * lo + vb1[e] * hi;
                    xm[4*q1+e] = va1[e] * hi + vb0[e] * lo;
                }
            }
        }
    }

    // ---- stage 4 (d=1): DPP quad_perm exchange; coeff rows 8,9 from LDS ----
    {
        const float* arow = &cf[(size_t)8 * 1024];
        const float* brow = &cf[(size_t)9 * 1024];
        #pragma unroll
        for (int c = 0; c < 4; ++c) {
            f4 va = *reinterpret_cast<const f4*>(&arow[swz(lane * 16 + 4 * c)]);
            f4 vb = *reinterpret_cast<const f4*>(&brow[swz((lane ^ 1) * 16 + 4 * c)]);
            #pragma unroll
            for (int m = 0; m < 2; ++m) {
                #pragma unroll
                for (int e = 0; e < 4; ++e) {
                    float v = x[m][4*c+e];
                    x[m][4*c+e] = va[e] * v + vb[e] * dppx<0xB1>(v);
                }
            }
        }
    }

    // ---- stages 5..9 (d=2,4,8,16,32): coeff rows 10..19 from LDS ----
    // exchange pipes: d=2,8 DPP | d=4 shfl (DS) | d=16,32 permlane builtin (VALU)
    #pragma unroll
    for (int i = 5; i < 10; ++i) {
        const int d = 1 << (i - 4);
        const float* arow = &cf[(size_t)(2*i)     * 1024];
        const float* brow = &cf[(size_t)(2*i + 1) * 1024];
        #pragma unroll
        for (int c = 0; c < 4; ++c) {
            f4 va = *reinterpret_cast<const f4*>(&arow[swz(lane * 16 + 4 * c)]);
            f4 vb = *reinterpret_cast<const f4*>(&brow[swz((lane ^ d) * 16 + 4 * c)]);
            #pragma unroll
            for (int m = 0; m < 2; ++m) {
                #pragma unroll
                for (int e = 0; e < 4; ++e) {
                    float v = x[m][4*c+e];
                    float xp = (d == 2)  ? dppx<0x4E>(v)
                             : (d == 8)  ? dppx<0x128>(v)
                             : (d == 16) ? xswap16(v)
                             : (d == 32) ? xswap32(v)
                             :             __shfl_xor(v, d, 64);   // d = 4
                    x[m][4*c+e] = va[e] * v + vb[e] * xp;
                }
            }
        }
    }

    // z write (R7-verified slot algebra) into this wave's private region.
    float* zz = &cf[20 * 1024 + (size_t)wave * 2048];  // 1024 f2 slots
    const int km0 = (lane & 7) << 1;                   // pair-preserving swizzle
    #pragma unroll
    for (int k = 0; k < 16; k += 2) {
        int pi = lane * 16 + (k ^ km0);
        f4 v = { x[0][k], x[1][k], x[0][k+1], x[1][k+1] };
        *reinterpret_cast<f4*>(&zz[2 * pi]) = v;
    }

    // epilogue (R7-verified): one b64 LDS read serves both samples; srv/scv
    // pipelined 1 deep ahead of the stores. Wave-private region, no barrier.
    const i4* srv = reinterpret_cast<const i4*>(src2);
    const f4* scv = reinterpret_cast<const f4*>(scale);
    f4* o0 = reinterpret_cast<f4*>(out + (size_t)sBase * 4096);
    f4* o1 = reinterpret_cast<f4*>(out + (size_t)(sBase + 1) * 4096);

    i4 si = srv[lane];
    f4 sc = scv[lane];
    #pragma unroll
    for (int it = 0; it < 16; ++it) {
        i4 si_c = si;
        f4 sc_c = sc;
        if (it + 1 < 16) {                      // prefetch next iteration
            si = srv[(it + 1) * 64 + lane];
            sc = scv[(it + 1) * 64 + lane];
        }
        int j4 = it * 64 + lane;
        f2 vx = *reinterpret_cast<const f2*>(&zz[2 * si_c.x]);
        f2 vy = *reinterpret_cast<const f2*>(&zz[2 * si_c.y]);
        f2 vz = *reinterpret_cast<const f2*>(&zz[2 * si_c.z]);
        f2 vw = *reinterpret_cast<const f2*>(&zz[2 * si_c.w]);
        f4 r0 = { sc_c.x * vx.x, sc_c.y * vy.x, sc_c.z * vz.x, sc_c.w * vw.x };
        f4 r1 = { sc_c.x * vx.y, sc_c.y * vy.y, sc_c.z * vz.y, sc_c.w * vw.y };
        o0[j4] = r0;
        o1[j4] = r1;
    }
}

extern "C" void kernel_launch(void* const* d_in, const int* in_sizes, int n_in,
                              void* d_out, int out_size, void* d_ws, size_t ws_size,
                              hipStream_t stream) {
    const float* inp  = (const float*)d_in[0];   // (8192, 1024) f32
    const float* lp   = (const float*)d_in[1];   // (24, 4096)  f32
    const int*   orow = (const int*)d_in[2];     // (4096,)     i32
    float* out = (float*)d_out;                  // (8192, 4096) f32

    float* scale = (float*)d_ws;                       // 4096 f32
    int*   src2  = (int*)((char*)d_ws + 4096 * 4);     // 4096 i32 (f2-slot idx)

    bfly_prep<<<16, 256, 0, stream>>>(lp, orow, scale, src2);
    bfly_main<<<512, 512, 0, stream>>>(inp, lp, scale, src2, out);
}